// Round 10
// baseline (71.898 us; speedup 1.0000x reference)
//
#include <hip/hip_runtime.h>

typedef float floatx4 __attribute__((ext_vector_type(4)));

// SMPL 24-joint tree ancestor tables (root-clipped to 0; joint 0's offset is 0
// so clipped slots contribute exactly 0).
// cA1 = parent, cA2 = 2nd ancestor, cA3 = 3rd, cA4 = 4th.
// Lane j's local sum L = v[j]+v[a1]+v[a2]+v[a3]; total = L + L[a4] is exact
// for every chain (max 8 non-root nodes), verified per-joint.
__device__ __constant__ int cA1[24] = {0,0,0,0,1,2,3,4,5,6,7,8,9,9,9,12,13,14,16,17,18,19,20,21};
__device__ __constant__ int cA2[24] = {0,0,0,0,0,0,0,1,2,3,4,5,6,6,6,9,9,9,13,14,16,17,18,19};
__device__ __constant__ int cA3[24] = {0,0,0,0,0,0,0,0,0,0,1,2,3,3,3,6,6,6,9,9,13,14,16,17};
__device__ __constant__ int cA4[24] = {0,0,0,0,0,0,0,0,0,0,0,0,0,0,0,3,3,3,6,6,9,9,13,14};

#define ITERS 16   // batches per 32-lane group per block

__device__ __forceinline__ void qrot_acc(const float4 q,
                                         const float ox, const float oy, const float oz,
                                         float& vx, float& vy, float& vz) {
    const float w = q.x, x = q.y, y = q.z, z = q.w;
    vx += (1.f - 2.f * (y * y + z * z)) * ox + (2.f * (x * y - z * w)) * oy + (2.f * (x * z + y * w)) * oz;
    vy += (2.f * (x * y + z * w)) * ox + (1.f - 2.f * (x * x + z * z)) * oy + (2.f * (y * z - x * w)) * oz;
    vz += (2.f * (x * z - y * w)) * ox + (2.f * (y * z + x * w)) * oy + (1.f - 2.f * (x * x + y * y)) * oz;
}

__global__ __launch_bounds__(256, 4) void fk_kernel(
    const float* __restrict__ rot,      // [B, 24, 4]
    const float* __restrict__ skel,     // [24, 3]
    float* __restrict__ out,            // [B, 24, 3]
    int B)
{
    const int tid = threadIdx.x;
    const int j   = tid & 31;           // joint lane within 32-lane group
    const int grp = tid >> 5;           // 0..7 batch-groups per block
    const int jc  = (j < 24) ? j : 0;

    const int a1 = cA1[jc], a2 = cA2[jc], a3 = cA3[jc], a4 = cA4[jc];

    // Loop-invariant rest-pose offsets for self + 3 nearest ancestors.
    const float sJx = skel[jc * 3 + 0], sJy = skel[jc * 3 + 1], sJz = skel[jc * 3 + 2];
    const float s1x = skel[a1 * 3 + 0], s1y = skel[a1 * 3 + 1], s1z = skel[a1 * 3 + 2];
    const float s2x = skel[a2 * 3 + 0], s2y = skel[a2 * 3 + 1], s2z = skel[a2 * 3 + 2];
    const float s3x = skel[a3 * 3 + 0], s3y = skel[a3 * 3 + 1], s3z = skel[a3 * 3 + 2];
    const float s4x = skel[a4 * 3 + 0], s4y = skel[a4 * 3 + 1], s4z = skel[a4 * 3 + 2];
    const float oSx = sJx - s1x, oSy = sJy - s1y, oSz = sJz - s1z;
    const float o1x = s1x - s2x, o1y = s1y - s2y, o1z = s1z - s2z;
    const float o2x = s2x - s3x, o2y = s2y - s3y, o2z = s2z - s3z;
    const float o3x = s3x - s4x, o3y = s3y - s4y, o3z = s3z - s4z;

    // Repack constants: dest lane j (j<18) stores floats [4j,4j+4) of its
    // group's 72-float output; sources sA=(4j)/3, sB=sA+1; case r=j%3.
    const int sA = (4 * j) / 3;
    const int sB = (sA < 23) ? sA + 1 : 23;
    const int r  = j % 3;

    const float4* __restrict__ rot4 = reinterpret_cast<const float4*>(rot);
    floatx4* __restrict__ out4 = reinterpret_cast<floatx4*>(out);

    const int base = blockIdx.x * (8 * ITERS);   // first batch of this block

#pragma unroll 4
    for (int it = 0; it < ITERS; ++it) {
        const int b = base + it * 8 + grp;
        if (b < B) {
            const size_t b24 = (size_t)b * 24;
            // Self + 3 nearest ancestors' quats: all within this batch's 384B
            // block -> L1 hits; lanes >=24 replicate joint 0 (harmless).
            const float4 qS = rot4[b24 + jc];
            const float4 q1 = rot4[b24 + a1];
            const float4 q2 = rot4[b24 + a2];
            const float4 q3 = rot4[b24 + a3];

            // Local 4-node chain sum (clipped slots have zero offsets -> +0).
            float vx = 0.f, vy = 0.f, vz = 0.f;
            qrot_acc(qS, oSx, oSy, oSz, vx, vy, vz);
            qrot_acc(q1, o1x, o1y, o1z, vx, vy, vz);
            qrot_acc(q2, o2x, o2y, o2z, vx, vy, vz);
            qrot_acc(q3, o3x, o3y, o3z, vx, vy, vz);

            // One jump: add the 4th ancestor's full (<=4-node) chain sum.
            const float cx = vx + __shfl(vx, a4, 32);
            const float cy = vy + __shfl(vy, a4, 32);
            const float cz = vz + __shfl(vz, a4, 32);

            // In-wave repack to dense float4 (6 shuffles + selects).
            const float axA = __shfl(cx, sA, 32), ayA = __shfl(cy, sA, 32), azA = __shfl(cz, sA, 32);
            const float axB = __shfl(cx, sB, 32), ayB = __shfl(cy, sB, 32), azB = __shfl(cz, sB, 32);

            const float o0 = (r == 0) ? axA : (r == 1) ? ayA : azA;
            const float o1 = (r == 0) ? ayA : (r == 1) ? azA : axB;
            const float o2 = (r == 0) ? azA : (r == 1) ? axB : ayB;
            const float o3 = (r == 0) ? axB : (r == 1) ? ayB : azB;

            // Dense, fully-covered, 64B-aligned wave store; nontemporal so the
            // output bypasses L2/L3 and the input stays L3-resident.
            if (j < 18) {
                floatx4 v; v.x = o0; v.y = o1; v.z = o2; v.w = o3;
                __builtin_nontemporal_store(v, out4 + (size_t)b * 18 + j);
            }
        }
    }
}

extern "C" void kernel_launch(void* const* d_in, const int* in_sizes, int n_in,
                              void* d_out, int out_size, void* d_ws, size_t ws_size,
                              hipStream_t stream) {
    const float* rot  = (const float*)d_in[0];   // [B, 24, 4] f32
    const float* skel = (const float*)d_in[1];   // [24, 3] f32
    float* out = (float*)d_out;                  // [B, 24, 3] f32

    const int B = in_sizes[0] / (24 * 4);        // 524288
    const int perBlock = 8 * ITERS;              // 128 batches per block
    const int grid = (B + perBlock - 1) / perBlock;   // 4096
    fk_kernel<<<grid, 256, 0, stream>>>(rot, skel, out, B);
}

// Round 12
// 58.927 us; speedup vs baseline: 1.2201x; 1.2201x over previous
//
#include <hip/hip_runtime.h>

typedef float floatx4 __attribute__((ext_vector_type(4)));

// SMPL 24-joint tree ancestor tables (root-clipped to 0; root's bone offset is
// 0 so clipped slots contribute exactly 0).
// cA1 = parent, cA2 = 2nd ancestor, cA4 = 4th ancestor.
// Lane j pair-sum P = v[j]+v[a1]; P2 = P + P[a2] covers 4 nodes; P4 = P2 +
// P2[a4] covers 8 — exact for every chain (max 8 non-root nodes).
__device__ __constant__ int cA1[24] = {0,0,0,0,1,2,3,4,5,6,7,8,9,9,9,12,13,14,16,17,18,19,20,21};
__device__ __constant__ int cA2[24] = {0,0,0,0,0,0,0,1,2,3,4,5,6,6,6,9,9,9,13,14,16,17,18,19};
__device__ __constant__ int cA4[24] = {0,0,0,0,0,0,0,0,0,0,0,0,0,0,0,3,3,3,6,6,9,9,13,14};

#define ITERS 16   // batches per 32-lane group per block

__device__ __forceinline__ void qrot_acc(const float4 q,
                                         const float ox, const float oy, const float oz,
                                         float& vx, float& vy, float& vz) {
    const float w = q.x, x = q.y, y = q.z, z = q.w;
    vx += (1.f - 2.f * (y * y + z * z)) * ox + (2.f * (x * y - z * w)) * oy + (2.f * (x * z + y * w)) * oz;
    vy += (2.f * (x * y + z * w)) * ox + (1.f - 2.f * (x * x + z * z)) * oy + (2.f * (y * z - x * w)) * oz;
    vz += (2.f * (x * z - y * w)) * ox + (2.f * (y * z + x * w)) * oy + (1.f - 2.f * (x * x + y * y)) * oz;
}

// Push-repack routing for round r (compile-time r, runtime lane j):
// flat float f = 3*joint + comp; round(f) = f mod 4; dest lane d = f >> 2.
// Active source with no float this round parks at 18+(j>>2); lanes >=24 park
// at themselves (24..31). Dest d receives float 4d+r in round r.
__device__ __forceinline__ void repack_const(int r, int j, int wavehalf,
                                             int& addr, int& comp) {
    int c = (r - 3 * j) & 3;
    int d;
    if (j < 24 && c < 3) { d = (3 * j + c) >> 2; }
    else if (j < 24)     { d = 18 + (j >> 2); c = 0; }
    else                 { d = j; c = 0; }
    addr = (wavehalf + d) << 2;      // ds_permute byte address
    comp = c;
}

__global__ __launch_bounds__(256, 8) void fk_kernel(
    const float* __restrict__ rot,      // [B, 24, 4]
    const float* __restrict__ skel,     // [24, 3]
    float* __restrict__ out,            // [B, 24, 3]
    int B)
{
    const int tid = threadIdx.x;
    const int j   = tid & 31;           // joint lane within 32-lane group
    const int grp = tid >> 5;           // 0..7 batch-groups per block
    const int jc  = (j < 24) ? j : 0;
    const int wavehalf = tid & 32;      // keep pushes within the 32-lane half

    const int a1 = cA1[jc], a2 = cA2[jc], a4 = cA4[jc];

    // Loop-invariant rest-pose bone offsets for self and parent.
    const float sJx = skel[jc * 3 + 0], sJy = skel[jc * 3 + 1], sJz = skel[jc * 3 + 2];
    const float s1x = skel[a1 * 3 + 0], s1y = skel[a1 * 3 + 1], s1z = skel[a1 * 3 + 2];
    const float s2x = skel[a2 * 3 + 0], s2y = skel[a2 * 3 + 1], s2z = skel[a2 * 3 + 2];
    const float oSx = sJx - s1x, oSy = sJy - s1y, oSz = sJz - s1z;
    const float oPx = s1x - s2x, oPy = s1y - s2y, oPz = s1z - s2z;

    // Push-repack per-round constants (named scalars; rule-#20 safe).
    int ad0, cp0, ad1, cp1, ad2, cp2, ad3, cp3;
    repack_const(0, j, wavehalf, ad0, cp0);
    repack_const(1, j, wavehalf, ad1, cp1);
    repack_const(2, j, wavehalf, ad2, cp2);
    repack_const(3, j, wavehalf, ad3, cp3);

    const float4* __restrict__ rot4 = reinterpret_cast<const float4*>(rot);
    floatx4* __restrict__ out4 = reinterpret_cast<floatx4*>(out);

    const int base = blockIdx.x * (8 * ITERS);   // first batch of this block

#pragma unroll 4
    for (int it = 0; it < ITERS; ++it) {
        const int b = base + it * 8 + grp;
        if (b < B) {
            const size_t b24 = (size_t)b * 24;
            const float4 qS = rot4[b24 + jc];    // self quat
            const float4 qP = rot4[b24 + a1];    // parent quat (same 384B block)

            // Local pair sum v[j] + v[a1].
            float vx = 0.f, vy = 0.f, vz = 0.f;
            qrot_acc(qS, oSx, oSy, oSz, vx, vy, vz);
            qrot_acc(qP, oPx, oPy, oPz, vx, vy, vz);

            // Two pointer jumps: 4-node then 8-node coverage (exact).
            const float x2 = vx + __shfl(vx, a2, 32);
            const float y2 = vy + __shfl(vy, a2, 32);
            const float z2 = vz + __shfl(vz, a2, 32);

            const float cx = x2 + __shfl(x2, a4, 32);
            const float cy = y2 + __shfl(y2, a4, 32);
            const float cz = z2 + __shfl(z2, a4, 32);

            // Push repack: 4 ds_permute rounds; dest lane d collects floats
            // 4d+0..3 of its group's 72-float output in round order.
            const float s0 = (cp0 == 0) ? cx : (cp0 == 1) ? cy : cz;
            const float s1 = (cp1 == 0) ? cx : (cp1 == 1) ? cy : cz;
            const float s2 = (cp2 == 0) ? cx : (cp2 == 1) ? cy : cz;
            const float s3 = (cp3 == 0) ? cx : (cp3 == 1) ? cy : cz;

            const float o0 = __int_as_float(__builtin_amdgcn_ds_permute(ad0, __float_as_int(s0)));
            const float o1 = __int_as_float(__builtin_amdgcn_ds_permute(ad1, __float_as_int(s1)));
            const float o2 = __int_as_float(__builtin_amdgcn_ds_permute(ad2, __float_as_int(s2)));
            const float o3 = __int_as_float(__builtin_amdgcn_ds_permute(ad3, __float_as_int(s3)));

            // Dense, fully-covered, 64B-aligned wave store; nontemporal so the
            // output bypasses L2/L3 and the input stays L3-resident.
            if (j < 18) {
                floatx4 v; v.x = o0; v.y = o1; v.z = o2; v.w = o3;
                __builtin_nontemporal_store(v, out4 + (size_t)b * 18 + j);
            }
        }
    }
}

extern "C" void kernel_launch(void* const* d_in, const int* in_sizes, int n_in,
                              void* d_out, int out_size, void* d_ws, size_t ws_size,
                              hipStream_t stream) {
    const float* rot  = (const float*)d_in[0];   // [B, 24, 4] f32
    const float* skel = (const float*)d_in[1];   // [24, 3] f32
    float* out = (float*)d_out;                  // [B, 24, 3] f32

    const int B = in_sizes[0] / (24 * 4);        // 524288
    const int perBlock = 8 * ITERS;              // 128 batches per block
    const int grid = (B + perBlock - 1) / perBlock;   // 4096
    fk_kernel<<<grid, 256, 0, stream>>>(rot, skel, out, B);
}